// Round 12
// baseline (366.517 us; speedup 1.0000x reference)
//
#include <hip/hip_runtime.h>
#include <cstdint>
#include <cstddef>

#define Tt 2048
#define Hh 1024
#define Ff 3584
#define Ee 8
#define ROWS_CAP 5120
#define MAXT 40

#define OFF_CTRL   0u
#define OFF_TOKE   4096u
#define OFF_TOKW   (4096u + 16384u)
#define OFF_ROWMAP 65536u
#define OFF_ROWW   98304u
#define OFF_XG     262144ull
#define OFF_G      10747904ull            // 5120*3584*2 = 36,700,160
#define OFF_W1T    47448064ull            // each 8*3584*1024*2 = 58,720,256
#define OFF_W3T    106168320ull
#define OFF_W2T    164888576ull           // ends 223,608,832 (<216MiB proven)

typedef __attribute__((ext_vector_type(8))) short bf16x8;
typedef __attribute__((ext_vector_type(4))) float f32x4;

__device__ __forceinline__ unsigned short f2bf(float f) {
  unsigned int u = __float_as_uint(f);
  u += 0x7fffu + ((u >> 16) & 1u);
  return (unsigned short)(u >> 16);
}

__device__ __forceinline__ unsigned pkbf(float a, float b) {
  unsigned r;
  asm("v_cvt_pk_bf16_f32 %0, %1, %2" : "=v"(r) : "v"(a), "v"(b));
  return r;
}

__device__ __forceinline__ void gload_lds16(const void* g, void* l) {
  auto gp = (const __attribute__((address_space(1))) char*)(uintptr_t)g;
  auto lp = (__attribute__((address_space(3))) char*)(uintptr_t)l;
  __builtin_amdgcn_global_load_lds(gp, lp, 16, 0, 0);
}

// GEMM LDS tile: rows x 32k bf16 (64 B/row); chunk gc at pos = gc ^ ((row>>1)&3).
__device__ __forceinline__ bf16x8 frg(const char* lds, int row, int gc) {
  return *(const bf16x8*)(lds + row * 64 + ((gc ^ ((row >> 1) & 3)) * 16));
}

// ---------------- router ----------------
__global__ __launch_bounds__(256) void router_kernel(
    const float* __restrict__ x, const float* __restrict__ gw,
    float* __restrict__ logits_out, int* __restrict__ tok_e,
    float* __restrict__ tok_w, int* __restrict__ ctrl) {
  const int lane = threadIdx.x & 63;
  const int t = blockIdx.x * 4 + (threadIdx.x >> 6);
  const float4* xp = (const float4*)(x + (size_t)t * Hh + lane * 16);
  float4 x0 = xp[0], x1 = xp[1], x2 = xp[2], x3 = xp[3];
  float lg[Ee];
#pragma unroll
  for (int e = 0; e < Ee; ++e) {
    const float4* gp = (const float4*)(gw + e * Hh + lane * 16);
    float4 g0 = gp[0], g1 = gp[1], g2 = gp[2], g3 = gp[3];
    float s = x0.x*g0.x + x0.y*g0.y + x0.z*g0.z + x0.w*g0.w
            + x1.x*g1.x + x1.y*g1.y + x1.z*g1.z + x1.w*g1.w
            + x2.x*g2.x + x2.y*g2.y + x2.z*g2.z + x2.w*g2.w
            + x3.x*g3.x + x3.y*g3.y + x3.z*g3.z + x3.w*g3.w;
#pragma unroll
    for (int o = 32; o; o >>= 1) s += __shfl_xor(s, o);
    lg[e] = s;
  }
  if (lane == 0) {
    float m = lg[0];
#pragma unroll
    for (int e = 1; e < Ee; ++e) m = fmaxf(m, lg[e]);
    float p[Ee];
#pragma unroll
    for (int e = 0; e < Ee; ++e) p[e] = expf(lg[e] - m);
    int a0 = 0;
#pragma unroll
    for (int e = 1; e < Ee; ++e) if (p[e] > p[a0]) a0 = e;
    int a1 = (a0 == 0) ? 1 : 0;
#pragma unroll
    for (int e = 0; e < Ee; ++e) if (e != a0 && p[e] > p[a1]) a1 = e;
    float rs = p[a0] + p[a1];
    float w0 = p[a0] / rs, w1 = p[a1] / rs;
#pragma unroll
    for (int e = 0; e < Ee; ++e) logits_out[(size_t)t * Ee + e] = lg[e];
    tok_e[t * 2] = a0; tok_e[t * 2 + 1] = a1;
    tok_w[t * 2] = w0; tok_w[t * 2 + 1] = w1;
    atomicAdd(&ctrl[a0], 1); atomicAdd(&ctrl[a1], 1);
  }
}

// offsets + flat m-tile table: ctrl[32+2*i]=e, ctrl[33+2*i]=row0 (-1 = dead)
__global__ void offsets_kernel(int* ctrl) {
  if (threadIdx.x == 0) {
    int acc = 0;
    for (int e = 0; e < Ee; ++e) {
      ctrl[16 + e] = acc;
      acc += ((ctrl[e] + 127) >> 7) << 7;
    }
    ctrl[16 + Ee] = acc;
    int idx = 0;
    for (int e = 0; e < Ee; ++e) {
      int nt = (ctrl[e] + 127) >> 7;
      for (int m = 0; m < nt && idx < MAXT; ++m) {
        ctrl[32 + 2 * idx] = e;
        ctrl[33 + 2 * idx] = ctrl[16 + e] + m * 128;
        ++idx;
      }
    }
    for (; idx < MAXT; ++idx) { ctrl[32 + 2 * idx] = 0; ctrl[33 + 2 * idx] = -1; }
  }
}

__global__ __launch_bounds__(512) void assign_kernel(
    int* ctrl, const int* __restrict__ tok_e, const float* __restrict__ tok_w,
    int* __restrict__ rowmap, float* __restrict__ roww) {
  int i = blockIdx.x * 512 + threadIdx.x;
  if (i < 2 * Tt) {
    int e = tok_e[i];
    int pos = atomicAdd(&ctrl[8 + e], 1);
    int r = ctrl[16 + e] + pos;
    rowmap[r] = i >> 1;
    roww[r] = tok_w[i];
  }
  if (i < Ee * 128) {
    int e = i >> 7, pd = i & 127;
    int o = ctrl[16 + e], o1 = ctrl[16 + e + 1], c = ctrl[e];
    int r = o + c + pd;
    if (r < o1) { rowmap[r] = -1; roww[r] = 0.f; }
  }
}

// ---------------- gather x rows -> bf16 Xg ----------------
__global__ __launch_bounds__(128) void gather_kernel(
    const float* __restrict__ x, const int* __restrict__ ctrl,
    const int* __restrict__ rowmap, unsigned short* __restrict__ Xg) {
  int r = blockIdx.x;
  if (r >= ctrl[16 + Ee]) return;
  int t = rowmap[r];
  int j = threadIdx.x;
  uint4 v = make_uint4(0u, 0u, 0u, 0u);
  if (t >= 0) {
    const float4* xp = (const float4*)(x + (size_t)t * Hh + j * 8);
    float4 a = xp[0], b = xp[1];
    v.x = (unsigned)f2bf(a.x) | ((unsigned)f2bf(a.y) << 16);
    v.y = (unsigned)f2bf(a.z) | ((unsigned)f2bf(a.w) << 16);
    v.z = (unsigned)f2bf(b.x) | ((unsigned)f2bf(b.y) << 16);
    v.w = (unsigned)f2bf(b.z) | ((unsigned)f2bf(b.w) << 16);
  }
  *(uint4*)(Xg + (size_t)r * Hh + j * 8) = v;
}

// -------- tc: fp32 in[R][C] -> bf16 out[C][R], tile 128r x 64c, 256 thr --------
// LDS [c][r] bf16, byte = c*256 + ((r*2) ^ (M(c)<<4)), M(c) = (c&7)^((c>>3)&7).
// Reads: 256 B/row segments. Writes: 256 B/out-row via 4 lanes x 64 B.
__global__ __launch_bounds__(256) void tc_all(
    const float* __restrict__ w1, const float* __restrict__ w3,
    const float* __restrict__ w2, unsigned short* __restrict__ w1T,
    unsigned short* __restrict__ w3T, unsigned short* __restrict__ w2T) {
  __shared__ alignas(16) char sT[64 * 256];
  const int z = blockIdx.z;
  const float* in = (z == 0) ? w1 : (z == 1) ? w3 : w2;
  unsigned short* out = (z == 0) ? w1T : (z == 1) ? w3T : w2T;
  const int R = (z == 2) ? Ff : Hh;           // in rows
  const int C = (z == 2) ? Hh : Ff;           // in cols
  const int tiles_c = (z == 2) ? 16 : 56;
  const int e = blockIdx.y;
  const int tr = blockIdx.x / tiles_c, tcc = blockIdx.x % tiles_c;
  const int r0g = tr * 128, c0 = tcc * 64;
  const float* src = in + (size_t)e * R * C;
  unsigned short* dst = out + (size_t)e * R * C;
  const int t = threadIdx.x;

  const int col4 = (t & 15) * 4, rb = (t >> 4) * 8;
  float4 v[8];
#pragma unroll
  for (int i = 0; i < 8; ++i)
    v[i] = *(const float4*)(src + (size_t)(r0g + rb + i) * C + c0 + col4);
#pragma unroll
  for (int j = 0; j < 4; ++j) {
    const float* a = (const float*)&v[0];
    int c = col4 + j;
    int M = (((c & 7) ^ ((c >> 3) & 7)) << 4);
    uint4 q;
    q.x = pkbf(((const float*)&v[0])[j], ((const float*)&v[1])[j]);
    q.y = pkbf(((const float*)&v[2])[j], ((const float*)&v[3])[j]);
    q.z = pkbf(((const float*)&v[4])[j], ((const float*)&v[5])[j]);
    q.w = pkbf(((const float*)&v[6])[j], ((const float*)&v[7])[j]);
    (void)a;
    *(uint4*)(sT + c * 256 + ((rb * 2) ^ M)) = q;
  }
  __syncthreads();
  const int oc = t >> 2, part = t & 3;
  const int M = (((oc & 7) ^ ((oc >> 3) & 7)) << 4);
#pragma unroll
  for (int i = 0; i < 4; ++i) {
    uint4 q = *(const uint4*)(sT + oc * 256 + ((i * 64 + part * 16) ^ M));
    *(uint4*)(dst + (size_t)(c0 + oc) * R + r0g + i * 32 + part * 8) = q;
  }
}

// ---------- h13: G = silu(Xg@w1T^T)*(Xg@w3T^T), 128x128, BK=32, 512 thr ----------
// Pure-glds staging for A, B1, B3 (R2/m97 semantics: __syncthreads drains).
__global__ __launch_bounds__(512, 4) void h13_gemm(
    const unsigned short* __restrict__ Xg, const unsigned short* __restrict__ w1T,
    const unsigned short* __restrict__ w3T, const int* __restrict__ ctrl,
    unsigned short* __restrict__ G) {
  __shared__ alignas(16) char sA[2][8192], sB1[2][8192], sB3[2][8192];
  int lin = blockIdx.y * 28 + blockIdx.x;          // 0..1119 = 8*140
  int wg = (lin & 7) * 140 + (lin >> 3);           // XCD chunk
  int ft = wg % 40, bx = wg / 40;                  // ft fast -> panel reuse in L2
  const int e = ctrl[32 + 2 * ft];
  const int row0 = ctrl[33 + 2 * ft];
  if (row0 < 0) return;
  const int n0 = bx * 128;
  const int tid = threadIdx.x, lane = tid & 63, wv = tid >> 6;
  const int wr = wv >> 2, wc = wv & 3;             // wave tile 64x32
  const unsigned short* w1e = w1T + (size_t)e * Ff * Hh;  // [F][H]
  const unsigned short* w3e = w3T + (size_t)e * Ff * Hh;
  f32x4 acc1[4][2] = {};
  f32x4 acc3[4][2] = {};
  const int srow = wv * 16 + (lane >> 2);
  const int sgc = (lane & 3) ^ ((lane >> 3) & 3);
  const unsigned short* gA  = Xg  + (size_t)(row0 + srow) * Hh + sgc * 8;
  const unsigned short* gB1 = w1e + (size_t)(n0 + srow) * Hh + sgc * 8;
  const unsigned short* gB3 = w3e + (size_t)(n0 + srow) * Hh + sgc * 8;

  gload_lds16(gA,  sA[0]  + wv * 1024);
  gload_lds16(gB1, sB1[0] + wv * 1024);
  gload_lds16(gB3, sB3[0] + wv * 1024);
  __syncthreads();

  for (int it = 0; it < 32; ++it) {
    const int cur = it & 1;
    if (it < 31) {
      const size_t ko = (size_t)(it + 1) * 32;
      gload_lds16(gA + ko,  sA[cur ^ 1]  + wv * 1024);
      gload_lds16(gB1 + ko, sB1[cur ^ 1] + wv * 1024);
      gload_lds16(gB3 + ko, sB3[cur ^ 1] + wv * 1024);
    }
    const int gc = lane >> 4;
    bf16x8 af[4];
#pragma unroll
    for (int mi = 0; mi < 4; ++mi)
      af[mi] = frg(sA[cur], wr * 64 + mi * 16 + (lane & 15), gc);
    __builtin_amdgcn_s_setprio(1);
#pragma unroll
    for (int ni = 0; ni < 2; ++ni) {
      bf16x8 b1 = frg(sB1[cur], wc * 32 + ni * 16 + (lane & 15), gc);
      bf16x8 b3 = frg(sB3[cur], wc * 32 + ni * 16 + (lane & 15), gc);
#pragma unroll
      for (int mi = 0; mi < 4; ++mi) {
        acc1[mi][ni] = __builtin_amdgcn_mfma_f32_16x16x32_bf16(af[mi], b1, acc1[mi][ni], 0, 0, 0);
        acc3[mi][ni] = __builtin_amdgcn_mfma_f32_16x16x32_bf16(af[mi], b3, acc3[mi][ni], 0, 0, 0);
      }
    }
    __builtin_amdgcn_s_setprio(0);
    __syncthreads();
  }
  const int rb = wr * 64 + 4 * (lane >> 4), cb = wc * 32 + (lane & 15);
#pragma unroll
  for (int mi = 0; mi < 4; ++mi)
#pragma unroll
    for (int ni = 0; ni < 2; ++ni)
#pragma unroll
      for (int r = 0; r < 4; ++r) {
        float h1 = acc1[mi][ni][r], h3 = acc3[mi][ni][r];
        float gv = h1 / (1.f + __expf(-h1)) * h3;
        G[(size_t)(row0 + rb + mi * 16 + r) * Ff + n0 + cb + ni * 16] = f2bf(gv);
      }
}

// ---------- ffn2: out[t] += w*(G@w2T^T), 128x128, BK=32, ksplit x4, pure glds ----------
__global__ __launch_bounds__(512, 4) void ffn2_gemm(
    const unsigned short* __restrict__ G, const unsigned short* __restrict__ w2T,
    const int* __restrict__ ctrl, const int* __restrict__ rowmap,
    const float* __restrict__ roww, float* __restrict__ out) {
  __shared__ alignas(16) char sA[2][8192], sB[2][8192];
  int lin = (blockIdx.z * MAXT + blockIdx.y) * 8 + blockIdx.x;  // 0..1279
  int wg = (lin & 7) * 160 + (lin >> 3);
  int ft = wg % 40, q = wg / 40;                   // q 0..31
  int bx = q & 7, ks = q >> 3;
  const int e = ctrl[32 + 2 * ft];
  const int row0 = ctrl[33 + 2 * ft];
  if (row0 < 0) return;
  const int n0 = bx * 128;
  const int kb = ks * (Ff / 4);                    // 896-wide K chunk, 28 iters
  const int tid = threadIdx.x, lane = tid & 63, wv = tid >> 6;
  const int wr = wv >> 2, wc = wv & 3;             // wave tile 64x32
  const unsigned short* w2e = w2T + (size_t)e * Ff * Hh;  // [H][F]
  f32x4 acc[4][2] = {};
  const int srow = wv * 16 + (lane >> 2);
  const int sgc = (lane & 3) ^ ((lane >> 3) & 3);
  const unsigned short* gA = G   + (size_t)(row0 + srow) * Ff + kb + sgc * 8;
  const unsigned short* gB = w2e + (size_t)(n0 + srow) * Ff + kb + sgc * 8;

  gload_lds16(gA, sA[0] + wv * 1024);
  gload_lds16(gB, sB[0] + wv * 1024);
  __syncthreads();

  const int NT = 28;
  for (int it = 0; it < NT; ++it) {
    const int cur = it & 1;
    if (it < NT - 1) {
      const size_t ko = (size_t)(it + 1) * 32;
      gload_lds16(gA + ko, sA[cur ^ 1] + wv * 1024);
      gload_lds16(gB + ko, sB[cur ^ 1] + wv * 1024);
    }
    const int gc = lane >> 4;
    bf16x8 af[4];
#pragma unroll
    for (int mi = 0; mi < 4; ++mi)
      af[mi] = frg(sA[cur], wr * 64 + mi * 16 + (lane & 15), gc);
    __builtin_amdgcn_s_setprio(1);
#pragma unroll
    for (int ni = 0; ni < 2; ++ni) {
      bf16x8 b = frg(sB[cur], wc * 32 + ni * 16 + (lane & 15), gc);
#pragma unroll
      for (int mi = 0; mi < 4; ++mi)
        acc[mi][ni] = __builtin_amdgcn_mfma_f32_16x16x32_bf16(af[mi], b, acc[mi][ni], 0, 0, 0);
    }
    __builtin_amdgcn_s_setprio(0);
    __syncthreads();
  }
  const int rb = wr * 64 + 4 * (lane >> 4), cb = wc * 32 + (lane & 15);
#pragma unroll
  for (int mi = 0; mi < 4; ++mi)
#pragma unroll
    for (int r = 0; r < 4; ++r) {
      int grow = row0 + rb + mi * 16 + r;
      int t = rowmap[grow];
      if (t < 0) continue;
      float wgt = roww[grow];
#pragma unroll
      for (int ni = 0; ni < 2; ++ni)
        atomicAdd(&out[(size_t)t * Hh + n0 + cb + ni * 16], wgt * acc[mi][ni][r]);
    }
}

extern "C" void kernel_launch(void* const* d_in, const int* in_sizes, int n_in,
                              void* d_out, int out_size, void* d_ws, size_t ws_size,
                              hipStream_t stream) {
  const float* x  = (const float*)d_in[0];
  const float* gw = (const float*)d_in[1];
  const float* w1 = (const float*)d_in[2];
  const float* w3 = (const float*)d_in[3];
  const float* w2 = (const float*)d_in[4];
  float* out = (float*)d_out;
  float* logits = out + (size_t)Tt * Hh;
  char* ws = (char*)d_ws;
  int* ctrl = (int*)(ws + OFF_CTRL);
  int* tok_e = (int*)(ws + OFF_TOKE);
  float* tok_w = (float*)(ws + OFF_TOKW);
  int* rowmap = (int*)(ws + OFF_ROWMAP);
  float* roww = (float*)(ws + OFF_ROWW);
  unsigned short* Xg  = (unsigned short*)(ws + OFF_XG);
  unsigned short* G   = (unsigned short*)(ws + OFF_G);
  unsigned short* w1T = (unsigned short*)(ws + OFF_W1T);
  unsigned short* w3T = (unsigned short*)(ws + OFF_W3T);
  unsigned short* w2T = (unsigned short*)(ws + OFF_W2T);

  hipMemsetAsync(ctrl, 0, 512, stream);
  hipMemsetAsync(out, 0, (size_t)Tt * Hh * sizeof(float), stream);
  router_kernel<<<Tt / 4, 256, 0, stream>>>(x, gw, logits, tok_e, tok_w, ctrl);
  offsets_kernel<<<1, 64, 0, stream>>>(ctrl);
  assign_kernel<<<8, 512, 0, stream>>>(ctrl, tok_e, tok_w, rowmap, roww);
  gather_kernel<<<ROWS_CAP, 128, 0, stream>>>(x, ctrl, rowmap, Xg);
  tc_all<<<dim3(448, Ee, 3), 256, 0, stream>>>(w1, w3, w2, w1T, w3T, w2T);
  h13_gemm<<<dim3(28, MAXT), 512, 0, stream>>>(Xg, w1T, w3T, ctrl, G);
  ffn2_gemm<<<dim3(8, MAXT, 4), 512, 0, stream>>>(G, w2T, ctrl, rowmap, roww, out);
}

// Round 13
// 343.616 us; speedup vs baseline: 1.0666x; 1.0666x over previous
//
#include <hip/hip_runtime.h>
#include <cstdint>
#include <cstddef>

#define Tt 2048
#define Hh 1024
#define Ff 3584
#define Ee 8
#define ROWS_CAP 5120
#define MAXT 40

#define OFF_CTRL   0u
#define OFF_TOKE   4096u
#define OFF_TOKW   (4096u + 16384u)
#define OFF_ROWMAP 65536u
#define OFF_ROWW   98304u
#define OFF_XG     262144ull
#define OFF_G      10747904ull
#define OFF_W1T    47448064ull
#define OFF_W3T    106168320ull
#define OFF_W2T    164888576ull

typedef __attribute__((ext_vector_type(8))) short bf16x8;
typedef __attribute__((ext_vector_type(4))) float f32x4;

__device__ __forceinline__ unsigned short f2bf(float f) {
  unsigned int u = __float_as_uint(f);
  u += 0x7fffu + ((u >> 16) & 1u);
  return (unsigned short)(u >> 16);
}

__device__ __forceinline__ unsigned pkbf(float a, float b) {
  unsigned r;
  asm("v_cvt_pk_bf16_f32 %0, %1, %2" : "=v"(r) : "v"(a), "v"(b));
  return r;
}

__device__ __forceinline__ void gload_lds16(const void* g, void* l) {
  auto gp = (const __attribute__((address_space(1))) char*)(uintptr_t)g;
  auto lp = (__attribute__((address_space(3))) char*)(uintptr_t)l;
  __builtin_amdgcn_global_load_lds(gp, lp, 16, 0, 0);
}

// GEMM LDS tile: rows x 32k bf16 (64 B/row); chunk gc at pos = gc ^ ((row>>1)&3).
__device__ __forceinline__ bf16x8 frg(const char* lds, int row, int gc) {
  return *(const bf16x8*)(lds + row * 64 + ((gc ^ ((row >> 1) & 3)) * 16));
}

// ---- tc tile (256-thread logical unit): fp32 [R][C] -> bf16 [C][R], 128r x 64c ----
// R12-proven. sT must be 16384 bytes.
__device__ __forceinline__ void tc_tile(const float* __restrict__ src,
                                        unsigned short* __restrict__ dst,
                                        int R, int C, int r0g, int c0,
                                        char* sT, int t) {
  const int col4 = (t & 15) * 4, rb = (t >> 4) * 8;
  float4 v[8];
#pragma unroll
  for (int i = 0; i < 8; ++i)
    v[i] = *(const float4*)(src + (size_t)(r0g + rb + i) * C + c0 + col4);
#pragma unroll
  for (int j = 0; j < 4; ++j) {
    int c = col4 + j;
    int M = (((c & 7) ^ ((c >> 3) & 7)) << 4);
    uint4 q;
    q.x = pkbf(((const float*)&v[0])[j], ((const float*)&v[1])[j]);
    q.y = pkbf(((const float*)&v[2])[j], ((const float*)&v[3])[j]);
    q.z = pkbf(((const float*)&v[4])[j], ((const float*)&v[5])[j]);
    q.w = pkbf(((const float*)&v[6])[j], ((const float*)&v[7])[j]);
    *(uint4*)(sT + c * 256 + ((rb * 2) ^ M)) = q;
  }
  __syncthreads();
  const int oc = t >> 2, part = t & 3;
  const int M = (((oc & 7) ^ ((oc >> 3) & 7)) << 4);
#pragma unroll
  for (int i = 0; i < 4; ++i) {
    uint4 q = *(const uint4*)(sT + oc * 256 + ((i * 64 + part * 16) ^ M));
    *(uint4*)(dst + (size_t)(c0 + oc) * R + r0g + i * 32 + part * 8) = q;
  }
}

// ---------------- K1: router (blocks 0..511)  ||  tc(w1) (blocks 512..4095) ----------------
__global__ __launch_bounds__(256) void router_tc1(
    const float* __restrict__ x, const float* __restrict__ gw,
    float* __restrict__ logits_out, int* __restrict__ tok_e,
    float* __restrict__ tok_w, int* __restrict__ ctrl,
    const float* __restrict__ w1, unsigned short* __restrict__ w1T) {
  __shared__ alignas(16) char sT[16384];
  if (blockIdx.x >= 512) {
    int b = blockIdx.x - 512;                 // 0..3583 ; 448 tiles/expert
    int e = b / 448, rem = b % 448;
    int tr = rem / 56, tcc = rem % 56;        // R=1024: 8 r-tiles; C=3584: 56 c-tiles
    tc_tile(w1 + (size_t)e * Hh * Ff, w1T + (size_t)e * Hh * Ff,
            Hh, Ff, tr * 128, tcc * 64, sT, threadIdx.x);
    return;
  }
  const int lane = threadIdx.x & 63;
  const int t = blockIdx.x * 4 + (threadIdx.x >> 6);
  const float4* xp = (const float4*)(x + (size_t)t * Hh + lane * 16);
  float4 x0 = xp[0], x1 = xp[1], x2 = xp[2], x3 = xp[3];
  float lg[Ee];
#pragma unroll
  for (int e = 0; e < Ee; ++e) {
    const float4* gp = (const float4*)(gw + e * Hh + lane * 16);
    float4 g0 = gp[0], g1 = gp[1], g2 = gp[2], g3 = gp[3];
    float s = x0.x*g0.x + x0.y*g0.y + x0.z*g0.z + x0.w*g0.w
            + x1.x*g1.x + x1.y*g1.y + x1.z*g1.z + x1.w*g1.w
            + x2.x*g2.x + x2.y*g2.y + x2.z*g2.z + x2.w*g2.w
            + x3.x*g3.x + x3.y*g3.y + x3.z*g3.z + x3.w*g3.w;
#pragma unroll
    for (int o = 32; o; o >>= 1) s += __shfl_xor(s, o);
    lg[e] = s;
  }
  if (lane == 0) {
    float m = lg[0];
#pragma unroll
    for (int e = 1; e < Ee; ++e) m = fmaxf(m, lg[e]);
    float p[Ee];
#pragma unroll
    for (int e = 0; e < Ee; ++e) p[e] = expf(lg[e] - m);
    int a0 = 0;
#pragma unroll
    for (int e = 1; e < Ee; ++e) if (p[e] > p[a0]) a0 = e;
    int a1 = (a0 == 0) ? 1 : 0;
#pragma unroll
    for (int e = 0; e < Ee; ++e) if (e != a0 && p[e] > p[a1]) a1 = e;
    float rs = p[a0] + p[a1];
    float w0 = p[a0] / rs, w1v = p[a1] / rs;
#pragma unroll
    for (int e = 0; e < Ee; ++e) logits_out[(size_t)t * Ee + e] = lg[e];
    tok_e[t * 2] = a0; tok_e[t * 2 + 1] = a1;
    tok_w[t * 2] = w0; tok_w[t * 2 + 1] = w1v;
    atomicAdd(&ctrl[a0], 1); atomicAdd(&ctrl[a1], 1);
  }
}

__global__ void offsets_kernel(int* ctrl) {
  if (threadIdx.x == 0) {
    int acc = 0;
    for (int e = 0; e < Ee; ++e) {
      ctrl[16 + e] = acc;
      acc += ((ctrl[e] + 127) >> 7) << 7;
    }
    ctrl[16 + Ee] = acc;
    int idx = 0;
    for (int e = 0; e < Ee; ++e) {
      int nt = (ctrl[e] + 127) >> 7;
      for (int m = 0; m < nt && idx < MAXT; ++m) {
        ctrl[32 + 2 * idx] = e;
        ctrl[33 + 2 * idx] = ctrl[16 + e] + m * 128;
        ++idx;
      }
    }
    for (; idx < MAXT; ++idx) { ctrl[32 + 2 * idx] = 0; ctrl[33 + 2 * idx] = -1; }
  }
}

__global__ __launch_bounds__(512) void assign_kernel(
    int* ctrl, const int* __restrict__ tok_e, const float* __restrict__ tok_w,
    int* __restrict__ rowmap, float* __restrict__ roww) {
  int i = blockIdx.x * 512 + threadIdx.x;
  if (i < 2 * Tt) {
    int e = tok_e[i];
    int pos = atomicAdd(&ctrl[8 + e], 1);
    int r = ctrl[16 + e] + pos;
    rowmap[r] = i >> 1;
    roww[r] = tok_w[i];
  }
  if (i < Ee * 128) {
    int e = i >> 7, pd = i & 127;
    int o = ctrl[16 + e], o1 = ctrl[16 + e + 1], c = ctrl[e];
    int r = o + c + pd;
    if (r < o1) { rowmap[r] = -1; roww[r] = 0.f; }
  }
}

// ---------------- K4: gather (blocks 0..2559)  ||  tc(w3) (2560..6143) ----------------
__global__ __launch_bounds__(256) void gather_tc3(
    const float* __restrict__ x, const int* __restrict__ ctrl,
    const int* __restrict__ rowmap, unsigned short* __restrict__ Xg,
    const float* __restrict__ w3, unsigned short* __restrict__ w3T) {
  __shared__ alignas(16) char sT[16384];
  if (blockIdx.x >= 2560) {
    int b = blockIdx.x - 2560;
    int e = b / 448, rem = b % 448;
    int tr = rem / 56, tcc = rem % 56;
    tc_tile(w3 + (size_t)e * Hh * Ff, w3T + (size_t)e * Hh * Ff,
            Hh, Ff, tr * 128, tcc * 64, sT, threadIdx.x);
    return;
  }
  int r = blockIdx.x * 2 + (threadIdx.x >> 7);
  int j = threadIdx.x & 127;
  if (r >= ctrl[16 + Ee]) return;
  int t = rowmap[r];
  uint4 v = make_uint4(0u, 0u, 0u, 0u);
  if (t >= 0) {
    const float4* xp = (const float4*)(x + (size_t)t * Hh + j * 8);
    float4 a = xp[0], b = xp[1];
    v.x = (unsigned)f2bf(a.x) | ((unsigned)f2bf(a.y) << 16);
    v.y = (unsigned)f2bf(a.z) | ((unsigned)f2bf(a.w) << 16);
    v.z = (unsigned)f2bf(b.x) | ((unsigned)f2bf(b.y) << 16);
    v.w = (unsigned)f2bf(b.z) | ((unsigned)f2bf(b.w) << 16);
  }
  *(uint4*)(Xg + (size_t)r * Hh + j * 8) = v;
}

// ---------------- K5: h13 (blocks 0..1119)  ||  tc(w2) (1120..2911, 2 tiles/block) ----------------
__global__ __launch_bounds__(512, 4) void h13_tc2(
    const unsigned short* __restrict__ Xg, const unsigned short* __restrict__ w1T,
    const unsigned short* __restrict__ w3T, const int* __restrict__ ctrl,
    unsigned short* __restrict__ G,
    const float* __restrict__ w2, unsigned short* __restrict__ w2T) {
  __shared__ alignas(16) char sLDS[49152];   // h13: 3x16K dbuf; tc2: 2x16K
  int lin = blockIdx.y * 28 + blockIdx.x;
  if (lin >= 1120) {
    int idx = lin - 1120;                    // 0..1791
    int s = threadIdx.x >> 8;                // 2 tiles per block
    int tile = idx * 2 + s;                  // 0..3583 ; w2: R=3584(28 r-tiles), C=1024(16 c-tiles)
    int e = tile / 448, rem = tile % 448;
    int tr = rem / 16, tcc = rem % 16;
    tc_tile(w2 + (size_t)e * Ff * Hh, w2T + (size_t)e * Ff * Hh,
            Ff, Hh, tr * 128, tcc * 64, sLDS + s * 16384, threadIdx.x & 255);
    return;
  }
  char* sA  = sLDS;                          // [2][8192]
  char* sB1 = sLDS + 16384;
  char* sB3 = sLDS + 32768;
  int wg = (lin & 7) * 140 + (lin >> 3);
  int ft = wg % 40, bx = wg / 40;
  const int e = ctrl[32 + 2 * ft];
  const int row0 = ctrl[33 + 2 * ft];
  if (row0 < 0) return;
  const int n0 = bx * 128;
  const int tid = threadIdx.x, lane = tid & 63, wv = tid >> 6;
  const int wr = wv >> 2, wc = wv & 3;
  const unsigned short* w1e = w1T + (size_t)e * Ff * Hh;
  const unsigned short* w3e = w3T + (size_t)e * Ff * Hh;
  f32x4 acc1[4][2] = {};
  f32x4 acc3[4][2] = {};
  const int srow = wv * 16 + (lane >> 2);
  const int sgc = (lane & 3) ^ ((lane >> 3) & 3);
  const unsigned short* gA  = Xg  + (size_t)(row0 + srow) * Hh + sgc * 8;
  const unsigned short* gB1 = w1e + (size_t)(n0 + srow) * Hh + sgc * 8;
  const unsigned short* gB3 = w3e + (size_t)(n0 + srow) * Hh + sgc * 8;

  gload_lds16(gA,  sA  + wv * 1024);
  gload_lds16(gB1, sB1 + wv * 1024);
  gload_lds16(gB3, sB3 + wv * 1024);
  __syncthreads();

  for (int it = 0; it < 32; ++it) {
    const int cur = it & 1;
    if (it < 31) {
      const size_t ko = (size_t)(it + 1) * 32;
      gload_lds16(gA + ko,  sA  + (cur ^ 1) * 8192 + wv * 1024);
      gload_lds16(gB1 + ko, sB1 + (cur ^ 1) * 8192 + wv * 1024);
      gload_lds16(gB3 + ko, sB3 + (cur ^ 1) * 8192 + wv * 1024);
    }
    const int gc = lane >> 4;
    bf16x8 af[4];
#pragma unroll
    for (int mi = 0; mi < 4; ++mi)
      af[mi] = frg(sA + cur * 8192, wr * 64 + mi * 16 + (lane & 15), gc);
    __builtin_amdgcn_s_setprio(1);
#pragma unroll
    for (int ni = 0; ni < 2; ++ni) {
      bf16x8 b1 = frg(sB1 + cur * 8192, wc * 32 + ni * 16 + (lane & 15), gc);
      bf16x8 b3 = frg(sB3 + cur * 8192, wc * 32 + ni * 16 + (lane & 15), gc);
#pragma unroll
      for (int mi = 0; mi < 4; ++mi) {
        acc1[mi][ni] = __builtin_amdgcn_mfma_f32_16x16x32_bf16(af[mi], b1, acc1[mi][ni], 0, 0, 0);
        acc3[mi][ni] = __builtin_amdgcn_mfma_f32_16x16x32_bf16(af[mi], b3, acc3[mi][ni], 0, 0, 0);
      }
    }
    __builtin_amdgcn_s_setprio(0);
    __syncthreads();
  }
  const int rb = wr * 64 + 4 * (lane >> 4), cb = wc * 32 + (lane & 15);
#pragma unroll
  for (int mi = 0; mi < 4; ++mi)
#pragma unroll
    for (int ni = 0; ni < 2; ++ni)
#pragma unroll
      for (int r = 0; r < 4; ++r) {
        float h1 = acc1[mi][ni][r], h3 = acc3[mi][ni][r];
        float gv = h1 / (1.f + __expf(-h1)) * h3;
        G[(size_t)(row0 + rb + mi * 16 + r) * Ff + n0 + cb + ni * 16] = f2bf(gv);
      }
}

// ---------------- K6: ffn2 (unchanged from R12) ----------------
__global__ __launch_bounds__(512, 4) void ffn2_gemm(
    const unsigned short* __restrict__ G, const unsigned short* __restrict__ w2T,
    const int* __restrict__ ctrl, const int* __restrict__ rowmap,
    const float* __restrict__ roww, float* __restrict__ out) {
  __shared__ alignas(16) char sA[2][8192], sB[2][8192];
  int lin = (blockIdx.z * MAXT + blockIdx.y) * 8 + blockIdx.x;
  int wg = (lin & 7) * 160 + (lin >> 3);
  int ft = wg % 40, q = wg / 40;
  int bx = q & 7, ks = q >> 3;
  const int e = ctrl[32 + 2 * ft];
  const int row0 = ctrl[33 + 2 * ft];
  if (row0 < 0) return;
  const int n0 = bx * 128;
  const int kb = ks * (Ff / 4);
  const int tid = threadIdx.x, lane = tid & 63, wv = tid >> 6;
  const int wr = wv >> 2, wc = wv & 3;
  const unsigned short* w2e = w2T + (size_t)e * Ff * Hh;
  f32x4 acc[4][2] = {};
  const int srow = wv * 16 + (lane >> 2);
  const int sgc = (lane & 3) ^ ((lane >> 3) & 3);
  const unsigned short* gA = G   + (size_t)(row0 + srow) * Ff + kb + sgc * 8;
  const unsigned short* gB = w2e + (size_t)(n0 + srow) * Ff + kb + sgc * 8;

  gload_lds16(gA, sA[0] + wv * 1024);
  gload_lds16(gB, sB[0] + wv * 1024);
  __syncthreads();

  const int NT = 28;
  for (int it = 0; it < NT; ++it) {
    const int cur = it & 1;
    if (it < NT - 1) {
      const size_t ko = (size_t)(it + 1) * 32;
      gload_lds16(gA + ko, sA[cur ^ 1] + wv * 1024);
      gload_lds16(gB + ko, sB[cur ^ 1] + wv * 1024);
    }
    const int gc = lane >> 4;
    bf16x8 af[4];
#pragma unroll
    for (int mi = 0; mi < 4; ++mi)
      af[mi] = frg(sA[cur], wr * 64 + mi * 16 + (lane & 15), gc);
    __builtin_amdgcn_s_setprio(1);
#pragma unroll
    for (int ni = 0; ni < 2; ++ni) {
      bf16x8 b = frg(sB[cur], wc * 32 + ni * 16 + (lane & 15), gc);
#pragma unroll
      for (int mi = 0; mi < 4; ++mi)
        acc[mi][ni] = __builtin_amdgcn_mfma_f32_16x16x32_bf16(af[mi], b, acc[mi][ni], 0, 0, 0);
    }
    __builtin_amdgcn_s_setprio(0);
    __syncthreads();
  }
  const int rb = wr * 64 + 4 * (lane >> 4), cb = wc * 32 + (lane & 15);
#pragma unroll
  for (int mi = 0; mi < 4; ++mi)
#pragma unroll
    for (int r = 0; r < 4; ++r) {
      int grow = row0 + rb + mi * 16 + r;
      int t = rowmap[grow];
      if (t < 0) continue;
      float wgt = roww[grow];
#pragma unroll
      for (int ni = 0; ni < 2; ++ni)
        atomicAdd(&out[(size_t)t * Hh + n0 + cb + ni * 16], wgt * acc[mi][ni][r]);
    }
}

extern "C" void kernel_launch(void* const* d_in, const int* in_sizes, int n_in,
                              void* d_out, int out_size, void* d_ws, size_t ws_size,
                              hipStream_t stream) {
  const float* x  = (const float*)d_in[0];
  const float* gw = (const float*)d_in[1];
  const float* w1 = (const float*)d_in[2];
  const float* w3 = (const float*)d_in[3];
  const float* w2 = (const float*)d_in[4];
  float* out = (float*)d_out;
  float* logits = out + (size_t)Tt * Hh;
  char* ws = (char*)d_ws;
  int* ctrl = (int*)(ws + OFF_CTRL);
  int* tok_e = (int*)(ws + OFF_TOKE);
  float* tok_w = (float*)(ws + OFF_TOKW);
  int* rowmap = (int*)(ws + OFF_ROWMAP);
  float* roww = (float*)(ws + OFF_ROWW);
  unsigned short* Xg  = (unsigned short*)(ws + OFF_XG);
  unsigned short* G   = (unsigned short*)(ws + OFF_G);
  unsigned short* w1T = (unsigned short*)(ws + OFF_W1T);
  unsigned short* w3T = (unsigned short*)(ws + OFF_W3T);
  unsigned short* w2T = (unsigned short*)(ws + OFF_W2T);

  hipMemsetAsync(ctrl, 0, 512, stream);
  hipMemsetAsync(out, 0, (size_t)Tt * Hh * sizeof(float), stream);
  router_tc1<<<512 + 3584, 256, 0, stream>>>(x, gw, logits, tok_e, tok_w, ctrl, w1, w1T);
  offsets_kernel<<<1, 64, 0, stream>>>(ctrl);
  assign_kernel<<<8, 512, 0, stream>>>(ctrl, tok_e, tok_w, rowmap, roww);
  gather_tc3<<<2560 + 3584, 256, 0, stream>>>(x, ctrl, rowmap, Xg, w3, w3T);
  h13_tc2<<<dim3(28, 104), 512, 0, stream>>>(Xg, w1T, w3T, ctrl, G, w2, w2T);  // 2912 blocks
  ffn2_gemm<<<dim3(8, MAXT, 4), 512, 0, stream>>>(G, w2T, ctrl, rowmap, roww, out);
}